// Round 1
// baseline (985.367 us; speedup 1.0000x reference)
//
#include <hip/hip_runtime.h>

// Fused SceneSelector:
//   k1: per-(image, 32x32 tile) block: stage x tile (44x44x3) in LDS,
//       conv1(3->3,5x5,relu) -> 40x40x3, conv2 -> 36x36x3, conv3(3->1) -> 32x32,
//       4 patch means (16x16 each) -> feat[B,256] in d_ws.
//   k2: per-image MLP: feat(256) -> 64 -> 8 -> softmax -> d_out.
//
// All fp32 (no fp32 MFMA on CDNA4; this is VALU FMA bound).
// Intermediate activations outside the image are forced to exact 0 to match
// the reference's per-conv zero SAME padding.

#define NTHREADS 256

template<int ICn, int OCn, int IP, int OP>
__device__ __forceinline__ void conv5(
    const float* __restrict__ sin,   // ICn x IP x IP (LDS)
    float*       __restrict__ sout,  // OCn x OP x OP (LDS)
    const float* __restrict__ w,     // OCn x ICn x 5 x 5 (global, uniform)
    const float* __restrict__ bias,  // OCn (global, uniform)
    int gy0, int gx0,                // global coords of sout[c][0][0]
    int tid)
{
    constexpr int QUADS = OP / 4;
    float bb[OCn];
#pragma unroll
    for (int c = 0; c < OCn; ++c) bb[c] = bias[c];

    for (int t = tid; t < OP * QUADS; t += NTHREADS) {
        const int y  = t / QUADS;
        const int x0 = (t % QUADS) * 4;

        float acc[OCn][4];
#pragma unroll
        for (int c = 0; c < OCn; ++c)
#pragma unroll
            for (int p = 0; p < 4; ++p) acc[c][p] = bb[c];

#pragma unroll
        for (int ic = 0; ic < ICn; ++ic) {
#pragma unroll
            for (int ky = 0; ky < 5; ++ky) {
                const float* row = sin + (ic * IP + y + ky) * IP + x0;
                // IP % 4 == 0 and x0 % 4 == 0 -> 16B aligned
                const float4 va = *reinterpret_cast<const float4*>(row);
                const float4 vb = *reinterpret_cast<const float4*>(row + 4);
                const float v[8] = {va.x, va.y, va.z, va.w, vb.x, vb.y, vb.z, vb.w};
#pragma unroll
                for (int kx = 0; kx < 5; ++kx) {
#pragma unroll
                    for (int c = 0; c < OCn; ++c) {
                        const float wv = w[((c * ICn + ic) * 5 + ky) * 5 + kx];
#pragma unroll
                        for (int p = 0; p < 4; ++p)
                            acc[c][p] = fmaf(v[p + kx], wv, acc[c][p]);
                    }
                }
            }
        }

        const int gy = gy0 + y;
        const bool rowok = (gy >= 0) & (gy < 256);
#pragma unroll
        for (int c = 0; c < OCn; ++c) {
#pragma unroll
            for (int p = 0; p < 4; ++p) {
                const int gx = gx0 + x0 + p;
                const bool ok = rowok & (gx >= 0) & (gx < 256);
                sout[(c * OP + y) * OP + x0 + p] = ok ? fmaxf(acc[c][p], 0.f) : 0.f;
            }
        }
    }
}

__global__ __launch_bounds__(NTHREADS) void fused_conv_feat(
    const float* __restrict__ x,
    const float* __restrict__ w1, const float* __restrict__ b1,
    const float* __restrict__ w2, const float* __restrict__ b2,
    const float* __restrict__ w3, const float* __restrict__ b3,
    float* __restrict__ feat)
{
    const int tile = blockIdx.x;       // 0..63
    const int b    = blockIdx.y;       // image
    const int by   = tile >> 3, bx = tile & 7;
    const int tid  = threadIdx.x;

    __shared__ __align__(16) float sIn[3][44][44];  // 23232 B
    __shared__ __align__(16) float sH1[3][40][40];  // 19200 B
    __shared__ __align__(16) float sH2[3][36][36];  // 15552 B
    __shared__ __align__(16) float sH3[32][32];     //  4096 B

    // ---- stage input tile (zero-padded) ----
    const int gy0 = by * 32 - 6, gx0 = bx * 32 - 6;
    for (int i = tid; i < 3 * 44 * 44; i += NTHREADS) {
        const int c   = i / (44 * 44);
        const int r   = (i / 44) % 44;
        const int col = i % 44;
        const int gy = gy0 + r, gx = gx0 + col;
        float v = 0.f;
        if (gy >= 0 && gy < 256 && gx >= 0 && gx < 256)
            v = x[(((size_t)b * 3 + c) * 256 + gy) * 256 + gx];
        sIn[c][r][col] = v;
    }
    __syncthreads();

    conv5<3, 3, 44, 40>(&sIn[0][0][0], &sH1[0][0][0], w1, b1, by * 32 - 4, bx * 32 - 4, tid);
    __syncthreads();
    conv5<3, 3, 40, 36>(&sH1[0][0][0], &sH2[0][0][0], w2, b2, by * 32 - 2, bx * 32 - 2, tid);
    __syncthreads();
    conv5<3, 1, 36, 32>(&sH2[0][0][0], &sH3[0][0],    w3, b3, by * 32,     bx * 32,     tid);
    __syncthreads();

    // ---- 4 patch means (16x16 each): wave w handles patch w ----
    const int p    = tid >> 6;     // 0..3
    const int lane = tid & 63;
    const int py = p >> 1, px = p & 1;
    float s = 0.f;
#pragma unroll
    for (int k = 0; k < 4; ++k) {
        const int idx = lane + k * 64;      // 0..255 within patch
        const int r = idx >> 4, cc = idx & 15;
        s += sH3[py * 16 + r][px * 16 + cc];
    }
#pragma unroll
    for (int off = 32; off > 0; off >>= 1) s += __shfl_down(s, off, 64);
    if (lane == 0) {
        const int j = by * 2 + py, i = bx * 2 + px;
        feat[(size_t)b * 256 + j * 16 + i] = s * (1.f / 256.f);
    }
}

__global__ __launch_bounds__(64) void mlp_head(
    const float* __restrict__ feat,
    const float* __restrict__ wl1, const float* __restrict__ bl1,
    const float* __restrict__ wl2, const float* __restrict__ bl2,
    float* __restrict__ out)
{
    const int b = blockIdx.x;
    const int t = threadIdx.x;   // 64 threads

    __shared__ float sF[256];
    __shared__ float sE[64];
    __shared__ float sL[8];
    __shared__ float sX[8];

    for (int i = t; i < 256; i += 64) sF[i] = feat[(size_t)b * 256 + i];
    __syncthreads();

    float acc = bl1[t];
    for (int k = 0; k < 256; ++k) acc = fmaf(sF[k], wl1[t * 256 + k], acc);
    sE[t] = acc;
    __syncthreads();

    if (t < 8) {
        float l = bl2[t];
#pragma unroll
        for (int k = 0; k < 64; ++k) l = fmaf(sE[k], wl2[t * 64 + k], l);
        sL[t] = l;
    }
    __syncthreads();

    if (t < 8) {
        float m = sL[0];
#pragma unroll
        for (int k = 1; k < 8; ++k) m = fmaxf(m, sL[k]);
        sX[t] = __expf(sL[t] - m) ; // fast exp fine within 2.5e-3
    }
    __syncthreads();

    if (t < 8) {
        float sum = 0.f;
#pragma unroll
        for (int k = 0; k < 8; ++k) sum += sX[k];
        out[(size_t)b * 8 + t] = sX[t] / sum;
    }
}

extern "C" void kernel_launch(void* const* d_in, const int* in_sizes, int n_in,
                              void* d_out, int out_size, void* d_ws, size_t ws_size,
                              hipStream_t stream) {
    const float* x   = (const float*)d_in[0];
    const float* w1  = (const float*)d_in[1];
    const float* b1  = (const float*)d_in[2];
    const float* w2  = (const float*)d_in[3];
    const float* b2  = (const float*)d_in[4];
    const float* w3  = (const float*)d_in[5];
    const float* b3  = (const float*)d_in[6];
    const float* wl1 = (const float*)d_in[7];
    const float* bl1 = (const float*)d_in[8];
    const float* wl2 = (const float*)d_in[9];
    const float* bl2 = (const float*)d_in[10];
    float* out  = (float*)d_out;
    float* feat = (float*)d_ws;   // 256*256 floats = 256 KB

    dim3 g1(64, 256);
    fused_conv_feat<<<g1, NTHREADS, 0, stream>>>(x, w1, b1, w2, b2, w3, b3, feat);
    mlp_head<<<256, 64, 0, stream>>>(feat, wl1, bl1, wl2, bl2, out);
}

// Round 2
// 670.456 us; speedup vs baseline: 1.4697x; 1.4697x over previous
//
#include <hip/hip_runtime.h>

// Fused SceneSelector, round 2.
//   k1: per-(image, 32x32 tile): stage 44x44x3 input in LDS, conv1->40x40x3,
//       conv2->36x36x3, conv3->32x32, 4 patch means -> feat[B,256] (d_ws).
//   k2: per-image MLP 256->64->8->softmax.
// LDS regions aliased: A = sIn(3x44x44) / {sH2(3x36 rows,stride40)+sH3(32x32)},
//                      B = sH1(3x40 rows,stride44).  44352 B -> 3 blocks/CU.

#define NTHREADS 256

template<int ICn, int OCn, int OP, int PX, int IS, int ICSZ, int OS, int OCSZ, bool MASK>
__device__ __forceinline__ void conv5(
    const float* __restrict__ sin, float* __restrict__ sout,
    const float* __restrict__ w, const float* __restrict__ bias,
    int gy0, int gx0, int tid)
{
    constexpr int QX    = OP / PX;
    constexpr int TASKS = OP * QX;
    constexpr int NV    = PX + 4;       // input floats per row segment

    float bb[OCn];
#pragma unroll
    for (int c = 0; c < OCn; ++c) bb[c] = bias[c];

    for (int t = tid; t < TASKS; t += NTHREADS) {
        const int y  = t / QX;
        const int x0 = (t - y * QX) * PX;

        float acc[OCn][PX];
#pragma unroll
        for (int c = 0; c < OCn; ++c)
#pragma unroll
            for (int p = 0; p < PX; ++p) acc[c][p] = bb[c];

#pragma unroll
        for (int ic = 0; ic < ICn; ++ic) {
#pragma unroll
            for (int ky = 0; ky < 5; ++ky) {
                const float* row = sin + ic * ICSZ + (y + ky) * IS + x0;
                float v[NV];
#pragma unroll
                for (int q = 0; q < NV / 4; ++q) {
                    const float4 t4 = *reinterpret_cast<const float4*>(row + 4 * q);
                    v[4 * q + 0] = t4.x; v[4 * q + 1] = t4.y;
                    v[4 * q + 2] = t4.z; v[4 * q + 3] = t4.w;
                }
#pragma unroll
                for (int kx = 0; kx < 5; ++kx)
#pragma unroll
                    for (int c = 0; c < OCn; ++c) {
                        const float wv = w[((c * ICn + ic) * 5 + ky) * 5 + kx];
#pragma unroll
                        for (int p = 0; p < PX; ++p)
                            acc[c][p] = fmaf(v[p + kx], wv, acc[c][p]);
                    }
            }
        }

        const int gy = gy0 + y;
#pragma unroll
        for (int c = 0; c < OCn; ++c)
#pragma unroll
            for (int q = 0; q < PX / 4; ++q) {
                float r[4];
#pragma unroll
                for (int j = 0; j < 4; ++j) {
                    float rv = fmaxf(acc[c][4 * q + j], 0.f);
                    if (MASK) {
                        const int gx = gx0 + x0 + 4 * q + j;
                        const bool ok = ((unsigned)gy < 256u) & ((unsigned)gx < 256u);
                        rv = ok ? rv : 0.f;
                    }
                    r[j] = rv;
                }
                *reinterpret_cast<float4*>(&sout[c * OCSZ + y * OS + x0 + 4 * q]) =
                    make_float4(r[0], r[1], r[2], r[3]);
            }
    }
}

__global__ __launch_bounds__(NTHREADS) void fused_conv_feat(
    const float* __restrict__ x,
    const float* __restrict__ w1, const float* __restrict__ b1,
    const float* __restrict__ w2, const float* __restrict__ b2,
    const float* __restrict__ w3, const float* __restrict__ b3,
    float* __restrict__ feat)
{
    const int tile = blockIdx.x;       // 0..63
    const int b    = blockIdx.y;       // image
    const int by   = tile >> 3, bx = tile & 7;
    const int tid  = threadIdx.x;

    __shared__ __align__(16) float lds[5808 + 5280];   // 44352 B
    float* sIn = lds;           // [3][44][44]
    float* sH1 = lds + 5808;    // [3][40 rows][stride 44]
    float* sH2 = lds;           // [3][36 rows][stride 40]  (aliases sIn)
    float* sH3 = lds + 4320;    // [32][32]                 (tail of region A)

    // ---- stage input tile (zero-padded), float2 ----
    const int gy0 = by * 32 - 6, gx0 = bx * 32 - 6;
    for (int i = tid; i < 3 * 44 * 22; i += NTHREADS) {
        const int c   = i / 968;            // 968 = 44*22
        const int rem = i - c * 968;
        const int r   = rem / 22;
        const int k   = rem - r * 22;
        const int gy = gy0 + r, gx = gx0 + 2 * k;
        float2 v = make_float2(0.f, 0.f);
        if ((unsigned)gy < 256u) {
            const float* src = x + (((size_t)b * 3 + c) * 256 + gy) * 256;
            if (gx >= 0 && gx + 1 < 256) {
                v = *reinterpret_cast<const float2*>(src + gx);
            } else {
                if ((unsigned)gx < 256u)       v.x = src[gx];
                if ((unsigned)(gx + 1) < 256u) v.y = src[gx + 1];
            }
        }
        *reinterpret_cast<float2*>(&sIn[(c * 44 + r) * 44 + 2 * k]) = v;
    }
    __syncthreads();

    // conv1: 3->3, in 44x44 (stride44), out 40 rows stride 44, 1x4 microtile
    conv5<3, 3, 40, 4, 44, 1936, 44, 1760, true>(sIn, sH1, w1, b1,
                                                 by * 32 - 4, bx * 32 - 4, tid);
    __syncthreads();
    // conv2: 3->3, in stride44, out 36 rows stride 40, 1x12 microtile (single pass)
    conv5<3, 3, 36, 12, 44, 1760, 40, 1440, true>(sH1, sH2, w2, b2,
                                                  by * 32 - 2, bx * 32 - 2, tid);
    __syncthreads();
    // conv3: 3->1, in stride40, out 32x32 (always interior -> no mask)
    conv5<3, 1, 32, 4, 40, 1440, 32, 1024, false>(sH2, sH3, w3, b3,
                                                  0, 0, tid);
    __syncthreads();

    // ---- 4 patch means (16x16 each): wave p handles patch p ----
    const int p    = tid >> 6;     // 0..3
    const int lane = tid & 63;
    const int py = p >> 1, px = p & 1;
    float s = 0.f;
#pragma unroll
    for (int k = 0; k < 4; ++k) {
        const int idx = lane + k * 64;      // 0..255 within patch
        const int r = idx >> 4, cc = idx & 15;
        s += sH3[(py * 16 + r) * 32 + px * 16 + cc];
    }
#pragma unroll
    for (int off = 32; off > 0; off >>= 1) s += __shfl_down(s, off, 64);
    if (lane == 0) {
        const int j = by * 2 + py, i = bx * 2 + px;
        feat[(size_t)b * 256 + j * 16 + i] = s * (1.f / 256.f);
    }
}

__global__ __launch_bounds__(64) void mlp_head(
    const float* __restrict__ feat,
    const float* __restrict__ wl1, const float* __restrict__ bl1,
    const float* __restrict__ wl2, const float* __restrict__ bl2,
    float* __restrict__ out)
{
    const int b = blockIdx.x;
    const int t = threadIdx.x;   // 64 threads

    __shared__ float sF[256];
    __shared__ float sE[64];
    __shared__ float sL[8];
    __shared__ float sX[8];

    for (int i = t; i < 256; i += 64) sF[i] = feat[(size_t)b * 256 + i];
    __syncthreads();

    float acc = bl1[t];
    for (int k = 0; k < 256; ++k) acc = fmaf(sF[k], wl1[t * 256 + k], acc);
    sE[t] = acc;
    __syncthreads();

    if (t < 8) {
        float l = bl2[t];
#pragma unroll
        for (int k = 0; k < 64; ++k) l = fmaf(sE[k], wl2[t * 64 + k], l);
        sL[t] = l;
    }
    __syncthreads();

    if (t < 8) {
        float m = sL[0];
#pragma unroll
        for (int k = 1; k < 8; ++k) m = fmaxf(m, sL[k]);
        sX[t] = __expf(sL[t] - m);
    }
    __syncthreads();

    if (t < 8) {
        float sum = 0.f;
#pragma unroll
        for (int k = 0; k < 8; ++k) sum += sX[k];
        out[(size_t)b * 8 + t] = sX[t] / sum;
    }
}

extern "C" void kernel_launch(void* const* d_in, const int* in_sizes, int n_in,
                              void* d_out, int out_size, void* d_ws, size_t ws_size,
                              hipStream_t stream) {
    const float* x   = (const float*)d_in[0];
    const float* w1  = (const float*)d_in[1];
    const float* b1  = (const float*)d_in[2];
    const float* w2  = (const float*)d_in[3];
    const float* b2  = (const float*)d_in[4];
    const float* w3  = (const float*)d_in[5];
    const float* b3  = (const float*)d_in[6];
    const float* wl1 = (const float*)d_in[7];
    const float* bl1 = (const float*)d_in[8];
    const float* wl2 = (const float*)d_in[9];
    const float* bl2 = (const float*)d_in[10];
    float* out  = (float*)d_out;
    float* feat = (float*)d_ws;   // 256*256 floats = 256 KB

    dim3 g1(64, 256);
    fused_conv_feat<<<g1, NTHREADS, 0, stream>>>(x, w1, b1, w2, b2, w3, b3, feat);
    mlp_head<<<256, 64, 0, stream>>>(feat, wl1, bl1, wl2, bl2, out);
}

// Round 3
// 521.316 us; speedup vs baseline: 1.8902x; 1.2861x over previous
//
#include <hip/hip_runtime.h>

// Fused SceneSelector, round 3.
//   k1: per-(image, 64x32 tile), 512 threads: stage 44x76x3 input in LDS,
//       conv1->40x72x3, conv2->36x68x3, conv3->32x64, 8 patch means
//       -> feat[B,256] (d_ws).
//   k2: per-image MLP 256->64->8->softmax.
// All stages single-pass, 2-row microtiles with 6-row sliding input window.
// All LDS planes stride 76 (16B-aligned rows, bank skew 12).
// Regions: A = sIn(3x44x76) reused by sH2(3x36x76); B = sH1(3x40x76) reused
// by sH3(32x64). Total 76608 B -> 2 blocks/CU (16 waves/CU).

#define NTHREADS 512

template<int ICn, int OCn, int OW, int OH, int IS, int ICSZ, int OS, int OCSZ, bool MASK>
__device__ __forceinline__ void conv5x5(
    const float* __restrict__ sin, float* __restrict__ sout,
    const float* __restrict__ w, const float* __restrict__ bias,
    int gy0, int gx0, int tid)
{
    constexpr int QX    = OW / 4;
    constexpr int RY    = OH / 2;
    constexpr int TASKS = QX * RY;

    if (tid < TASKS) {
        const int ry = tid / QX;
        const int qx = tid - ry * QX;
        const int y0 = ry * 2;
        const int x0 = qx * 4;

        float acc[2][OCn][4];
#pragma unroll
        for (int c = 0; c < OCn; ++c) {
            const float bb = bias[c];
#pragma unroll
            for (int p = 0; p < 4; ++p) { acc[0][c][p] = bb; acc[1][c][p] = bb; }
        }

#pragma unroll
        for (int ic = 0; ic < ICn; ++ic) {
            const float* base = sin + ic * ICSZ + y0 * IS + x0;
#pragma unroll
            for (int r = 0; r < 6; ++r) {           // input rows y0+r
                const float4 a4 = *reinterpret_cast<const float4*>(base + r * IS);
                const float4 b4 = *reinterpret_cast<const float4*>(base + r * IS + 4);
                const float v[8] = {a4.x, a4.y, a4.z, a4.w, b4.x, b4.y, b4.z, b4.w};
#pragma unroll
                for (int kx = 0; kx < 5; ++kx) {
#pragma unroll
                    for (int c = 0; c < OCn; ++c) {
                        if (r < 5) {                // ky = r for output row 0
                            const float wv = w[((c * ICn + ic) * 5 + r) * 5 + kx];
#pragma unroll
                            for (int p = 0; p < 4; ++p)
                                acc[0][c][p] = fmaf(v[p + kx], wv, acc[0][c][p]);
                        }
                        if (r >= 1) {               // ky = r-1 for output row 1
                            const float wv = w[((c * ICn + ic) * 5 + (r - 1)) * 5 + kx];
#pragma unroll
                            for (int p = 0; p < 4; ++p)
                                acc[1][c][p] = fmaf(v[p + kx], wv, acc[1][c][p]);
                        }
                    }
                }
            }
        }

#pragma unroll
        for (int rr = 0; rr < 2; ++rr) {
            const int gy = gy0 + y0 + rr;
#pragma unroll
            for (int c = 0; c < OCn; ++c) {
                float o[4];
#pragma unroll
                for (int p = 0; p < 4; ++p) {
                    float rv = fmaxf(acc[rr][c][p], 0.f);
                    if (MASK) {
                        const int gx = gx0 + x0 + p;
                        const bool ok = ((unsigned)gy < 256u) & ((unsigned)gx < 256u);
                        rv = ok ? rv : 0.f;
                    }
                    o[p] = rv;
                }
                *reinterpret_cast<float4*>(&sout[c * OCSZ + (y0 + rr) * OS + x0]) =
                    make_float4(o[0], o[1], o[2], o[3]);
            }
        }
    }
}

__global__ __launch_bounds__(NTHREADS) void fused_conv_feat(
    const float* __restrict__ x,
    const float* __restrict__ w1, const float* __restrict__ b1,
    const float* __restrict__ w2, const float* __restrict__ b2,
    const float* __restrict__ w3, const float* __restrict__ b3,
    float* __restrict__ feat)
{
    const int tile = blockIdx.x;       // 0..31
    const int b    = blockIdx.y;       // image
    const int tx   = tile & 3, ty = tile >> 2;   // tile = ty*4+tx; 64 wide, 32 tall
    const int tid  = threadIdx.x;

    __shared__ __align__(16) float lds[10032 + 9120];  // 76608 B
    float* sIn = lds;            // 3 x 44 x stride76  (CSZ 3344)
    float* sH1 = lds + 10032;    // 3 x 40 x stride76  (CSZ 3040)
    float* sH2 = lds;            // 3 x 36 x stride76  (CSZ 2736), aliases sIn
    float* sH3 = lds + 10032;    // 32 x 64, aliases sH1

    // ---- stage input tile (zero-padded), float2, rows of 38 float2 ----
    const int gy0s = ty * 32 - 6, gx0s = tx * 64 - 6;
    for (int i = tid; i < 3 * 44 * 38; i += NTHREADS) {
        const int c   = i / 1672;            // 1672 = 44*38
        const int rem = i - c * 1672;
        const int r   = rem / 38;
        const int k   = rem - r * 38;
        const int gy = gy0s + r, gx = gx0s + 2 * k;
        float2 v = make_float2(0.f, 0.f);
        if ((unsigned)gy < 256u) {
            const float* src = x + (((size_t)b * 3 + c) * 256 + gy) * 256;
            if (gx >= 0 && gx + 1 < 256) {
                v = *reinterpret_cast<const float2*>(src + gx);
            } else {
                if ((unsigned)gx < 256u)       v.x = src[gx];
                if ((unsigned)(gx + 1) < 256u) v.y = src[gx + 1];
            }
        }
        *reinterpret_cast<float2*>(&sIn[c * 3344 + r * 76 + 2 * k]) = v;
    }
    __syncthreads();

    // conv1: 3->3, out 40x72 (origin ty*32-4, tx*64-4)
    conv5x5<3, 3, 72, 40, 76, 3344, 76, 3040, true>(sIn, sH1, w1, b1,
                                                    ty * 32 - 4, tx * 64 - 4, tid);
    __syncthreads();
    // conv2: 3->3, out 36x68 (origin ty*32-2, tx*64-2)
    conv5x5<3, 3, 68, 36, 76, 3040, 76, 2736, true>(sH1, sH2, w2, b2,
                                                    ty * 32 - 2, tx * 64 - 2, tid);
    __syncthreads();
    // conv3: 3->1, out 32x64 (always interior -> no mask), stride 64
    conv5x5<3, 1, 64, 32, 76, 2736, 64, 2048, false>(sH2, sH3, w3, b3,
                                                     0, 0, tid);
    __syncthreads();

    // ---- 8 patch means (16x16 each): wave p handles patch p (2x4 grid) ----
    const int wv   = tid >> 6;     // 0..7
    const int lane = tid & 63;
    const int py = wv >> 2, px = wv & 3;
    float s = 0.f;
#pragma unroll
    for (int k = 0; k < 4; ++k) {
        const int idx = lane + k * 64;      // 0..255 within patch
        const int r = idx >> 4, cc = idx & 15;
        s += sH3[(py * 16 + r) * 64 + px * 16 + cc];
    }
#pragma unroll
    for (int off = 32; off > 0; off >>= 1) s += __shfl_down(s, off, 64);
    if (lane == 0) {
        const int j = ty * 2 + py, i = tx * 4 + px;
        feat[(size_t)b * 256 + j * 16 + i] = s * (1.f / 256.f);
    }
}

__global__ __launch_bounds__(64) void mlp_head(
    const float* __restrict__ feat,
    const float* __restrict__ wl1, const float* __restrict__ bl1,
    const float* __restrict__ wl2, const float* __restrict__ bl2,
    float* __restrict__ out)
{
    const int b = blockIdx.x;
    const int t = threadIdx.x;   // 64 threads

    __shared__ float sF[256];
    __shared__ float sE[64];
    __shared__ float sL[8];
    __shared__ float sX[8];

    for (int i = t; i < 256; i += 64) sF[i] = feat[(size_t)b * 256 + i];
    __syncthreads();

    float acc = bl1[t];
    for (int k = 0; k < 256; ++k) acc = fmaf(sF[k], wl1[t * 256 + k], acc);
    sE[t] = acc;
    __syncthreads();

    if (t < 8) {
        float l = bl2[t];
#pragma unroll
        for (int k = 0; k < 64; ++k) l = fmaf(sE[k], wl2[t * 64 + k], l);
        sL[t] = l;
    }
    __syncthreads();

    if (t < 8) {
        float m = sL[0];
#pragma unroll
        for (int k = 1; k < 8; ++k) m = fmaxf(m, sL[k]);
        sX[t] = __expf(sL[t] - m);
    }
    __syncthreads();

    if (t < 8) {
        float sum = 0.f;
#pragma unroll
        for (int k = 0; k < 8; ++k) sum += sX[k];
        out[(size_t)b * 8 + t] = sX[t] / sum;
    }
}

extern "C" void kernel_launch(void* const* d_in, const int* in_sizes, int n_in,
                              void* d_out, int out_size, void* d_ws, size_t ws_size,
                              hipStream_t stream) {
    const float* x   = (const float*)d_in[0];
    const float* w1  = (const float*)d_in[1];
    const float* b1  = (const float*)d_in[2];
    const float* w2  = (const float*)d_in[3];
    const float* b2  = (const float*)d_in[4];
    const float* w3  = (const float*)d_in[5];
    const float* b3  = (const float*)d_in[6];
    const float* wl1 = (const float*)d_in[7];
    const float* bl1 = (const float*)d_in[8];
    const float* wl2 = (const float*)d_in[9];
    const float* bl2 = (const float*)d_in[10];
    float* out  = (float*)d_out;
    float* feat = (float*)d_ws;   // 256*256 floats = 256 KB

    dim3 g1(32, 256);
    fused_conv_feat<<<g1, NTHREADS, 0, stream>>>(x, w1, b1, w2, b2, w3, b3, feat);
    mlp_head<<<256, 64, 0, stream>>>(feat, wl1, bl1, wl2, bl2, out);
}

// Round 4
// 449.866 us; speedup vs baseline: 2.1904x; 1.1588x over previous
//
#include <hip/hip_runtime.h>
#include <hip/hip_bf16.h>

// Round 4: split per-stage kernels, bf16 intermediates in d_ws.
//   conv1: x(f32) -> h1(bf16), conv2: h1 -> h2(bf16), conv3+pool: h2 -> feat(f32),
//   mlp: feat -> softmax out. Falls back to the round-3 fused kernel if ws_size
//   is too small for h1+h2 (2 x 100.66 MB + 256 KB feat).
// Conv kernels: 256 threads, 64x32 output tile, EXACTLY 256 tasks of
// 2 rows x 4 cols (x OC ch) -> zero wave imbalance, 1 barrier, 29.4 KB LDS.

#define CT 256

static __device__ __forceinline__ unsigned short f2bf(float f) {
    __hip_bfloat16 h = __float2bfloat16(f);
    return *reinterpret_cast<unsigned short*>(&h);
}
static __device__ __forceinline__ float bf2f(unsigned short u) {
    __hip_bfloat16 h;
    *reinterpret_cast<unsigned short*>(&h) = u;
    return __bfloat162float(h);
}

// ---------------- split-path conv kernel ----------------
template<bool IN_BF16, int OC, bool POOL>
__global__ __launch_bounds__(CT) void conv_stage(
    const void* __restrict__ in_,
    const float* __restrict__ w, const float* __restrict__ bias,
    unsigned short* __restrict__ out_, float* __restrict__ feat)
{
    const int tx = blockIdx.x;     // 0..3   (x tiles of 64)
    const int ty = blockIdx.y;     // 0..7   (y tiles of 32)
    const int b  = blockIdx.z;     // image
    const int tid = threadIdx.x;

    __shared__ __align__(16) float sIn[3 * 36 * 68];   // 29376 B
    __shared__ float sPartial[16];

    const int gy0 = ty * 32, gx0 = tx * 64;

    // ---- stage 36 rows x 68 cols x 3 ch (zero-padded), 2 elems/iter ----
    for (int i = tid; i < 3 * 36 * 34; i += CT) {
        const int c   = i / 1224;              // 1224 = 36*34
        const int rem = i - c * 1224;
        const int r   = rem / 34;
        const int k   = rem - r * 34;
        const int gy  = gy0 - 2 + r;
        const int gx  = gx0 - 2 + 2 * k;
        float2 v = make_float2(0.f, 0.f);
        if ((unsigned)gy < 256u) {
            if (!IN_BF16) {
                const float* src = (const float*)in_ + (((size_t)b * 3 + c) * 256 + gy) * 256;
                if (gx >= 0 && gx + 1 < 256) {
                    v = *reinterpret_cast<const float2*>(src + gx);
                } else {
                    if ((unsigned)gx < 256u)       v.x = src[gx];
                    if ((unsigned)(gx + 1) < 256u) v.y = src[gx + 1];
                }
            } else {
                const unsigned short* src =
                    (const unsigned short*)in_ + (((size_t)b * 3 + c) * 256 + gy) * 256;
                if (gx >= 0 && gx + 1 < 256) {
                    const unsigned int u = *reinterpret_cast<const unsigned int*>(src + gx);
                    v.x = bf2f((unsigned short)(u & 0xffffu));
                    v.y = bf2f((unsigned short)(u >> 16));
                } else {
                    if ((unsigned)gx < 256u)       v.x = bf2f(src[gx]);
                    if ((unsigned)(gx + 1) < 256u) v.y = bf2f(src[gx + 1]);
                }
            }
        }
        *reinterpret_cast<float2*>(&sIn[(c * 36 + r) * 68 + 2 * k]) = v;
    }
    __syncthreads();

    // ---- compute: task (ry,qx), 2 rows x 4 cols x OC ----
    const int ry = tid >> 4, qx = tid & 15;
    const int y0 = ry * 2,  x0 = qx * 4;

    float acc[2][OC][4];
#pragma unroll
    for (int c = 0; c < OC; ++c) {
        const float bb = bias[c];
#pragma unroll
        for (int p = 0; p < 4; ++p) { acc[0][c][p] = bb; acc[1][c][p] = bb; }
    }

#pragma unroll
    for (int ic = 0; ic < 3; ++ic) {
        const float* base = &sIn[ic * 2448 + y0 * 68 + x0];
        float v[6][8];
#pragma unroll
        for (int rw = 0; rw < 6; ++rw) {
            const float4 a4 = *reinterpret_cast<const float4*>(base + rw * 68);
            const float4 b4 = *reinterpret_cast<const float4*>(base + rw * 68 + 4);
            v[rw][0] = a4.x; v[rw][1] = a4.y; v[rw][2] = a4.z; v[rw][3] = a4.w;
            v[rw][4] = b4.x; v[rw][5] = b4.y; v[rw][6] = b4.z; v[rw][7] = b4.w;
        }
#pragma unroll
        for (int rw = 0; rw < 6; ++rw)
#pragma unroll
            for (int kx = 0; kx < 5; ++kx)
#pragma unroll
                for (int c = 0; c < OC; ++c) {
                    if (rw < 5) {
                        const float wv = w[((c * 3 + ic) * 5 + rw) * 5 + kx];
#pragma unroll
                        for (int p = 0; p < 4; ++p)
                            acc[0][c][p] = fmaf(v[rw][p + kx], wv, acc[0][c][p]);
                    }
                    if (rw >= 1) {
                        const float wv = w[((c * 3 + ic) * 5 + (rw - 1)) * 5 + kx];
#pragma unroll
                        for (int p = 0; p < 4; ++p)
                            acc[1][c][p] = fmaf(v[rw][p + kx], wv, acc[1][c][p]);
                    }
                }
    }

    if (!POOL) {
        // write bf16 NCHW, 8B per (row,ch): lanes qx 0..15 contiguous 128B
#pragma unroll
        for (int rr = 0; rr < 2; ++rr) {
            const int gy = gy0 + y0 + rr;
#pragma unroll
            for (int c = 0; c < OC; ++c) {
                const unsigned int lo =
                    (unsigned int)f2bf(fmaxf(acc[rr][c][0], 0.f)) |
                    ((unsigned int)f2bf(fmaxf(acc[rr][c][1], 0.f)) << 16);
                const unsigned int hi =
                    (unsigned int)f2bf(fmaxf(acc[rr][c][2], 0.f)) |
                    ((unsigned int)f2bf(fmaxf(acc[rr][c][3], 0.f)) << 16);
                unsigned short* dst =
                    out_ + (((size_t)b * OC + c) * 256 + gy) * 256 + gx0 + x0;
                *reinterpret_cast<uint2*>(dst) = make_uint2(lo, hi);
            }
        }
    } else {
        // per-thread 8 px all belong to one 16x16 patch: py=ry>>3, px=qx>>2
        float s = 0.f;
#pragma unroll
        for (int rr = 0; rr < 2; ++rr)
#pragma unroll
            for (int p = 0; p < 4; ++p) s += fmaxf(acc[rr][0][p], 0.f);
        // deterministic butterfly over the 16 lanes sharing a patch:
        // lanes differ in p-group (l&3 via xor 1,2) and ry (l>>4 via xor 16,32)
        s += __shfl_xor(s, 1, 64);
        s += __shfl_xor(s, 2, 64);
        s += __shfl_xor(s, 16, 64);
        s += __shfl_xor(s, 32, 64);
        const int wv = tid >> 6, l = tid & 63;
        if ((l & 3) == 0 && l < 16) sPartial[wv * 4 + (l >> 2)] = s;
        __syncthreads();
        if (tid < 8) {
            const int py = tid >> 2, px = tid & 3;
            const float v2 = sPartial[(2 * py) * 4 + px] + sPartial[(2 * py + 1) * 4 + px];
            const int j = ty * 2 + py, i = tx * 4 + px;
            feat[(size_t)b * 256 + j * 16 + i] = v2 * (1.f / 256.f);
        }
    }
}

// ---------------- fused fallback (round-3 kernel) ----------------
#define NTHREADS 512

template<int ICn, int OCn, int OW, int OH, int IS, int ICSZ, int OS, int OCSZ, bool MASK>
__device__ __forceinline__ void conv5x5(
    const float* __restrict__ sin, float* __restrict__ sout,
    const float* __restrict__ w, const float* __restrict__ bias,
    int gy0, int gx0, int tid)
{
    constexpr int QX = OW / 4;
    constexpr int RY = OH / 2;
    constexpr int TASKS = QX * RY;
    if (tid < TASKS) {
        const int ry = tid / QX;
        const int qx = tid - ry * QX;
        const int y0 = ry * 2, x0 = qx * 4;
        float acc[2][OCn][4];
#pragma unroll
        for (int c = 0; c < OCn; ++c) {
            const float bb = bias[c];
#pragma unroll
            for (int p = 0; p < 4; ++p) { acc[0][c][p] = bb; acc[1][c][p] = bb; }
        }
#pragma unroll
        for (int ic = 0; ic < ICn; ++ic) {
            const float* base = sin + ic * ICSZ + y0 * IS + x0;
#pragma unroll
            for (int r = 0; r < 6; ++r) {
                const float4 a4 = *reinterpret_cast<const float4*>(base + r * IS);
                const float4 b4 = *reinterpret_cast<const float4*>(base + r * IS + 4);
                const float v[8] = {a4.x, a4.y, a4.z, a4.w, b4.x, b4.y, b4.z, b4.w};
#pragma unroll
                for (int kx = 0; kx < 5; ++kx)
#pragma unroll
                    for (int c = 0; c < OCn; ++c) {
                        if (r < 5) {
                            const float wv = w[((c * ICn + ic) * 5 + r) * 5 + kx];
#pragma unroll
                            for (int p = 0; p < 4; ++p)
                                acc[0][c][p] = fmaf(v[p + kx], wv, acc[0][c][p]);
                        }
                        if (r >= 1) {
                            const float wv = w[((c * ICn + ic) * 5 + (r - 1)) * 5 + kx];
#pragma unroll
                            for (int p = 0; p < 4; ++p)
                                acc[1][c][p] = fmaf(v[p + kx], wv, acc[1][c][p]);
                        }
                    }
            }
        }
#pragma unroll
        for (int rr = 0; rr < 2; ++rr) {
            const int gy = gy0 + y0 + rr;
#pragma unroll
            for (int c = 0; c < OCn; ++c) {
                float o[4];
#pragma unroll
                for (int p = 0; p < 4; ++p) {
                    float rv = fmaxf(acc[rr][c][p], 0.f);
                    if (MASK) {
                        const int gx = gx0 + x0 + p;
                        const bool ok = ((unsigned)gy < 256u) & ((unsigned)gx < 256u);
                        rv = ok ? rv : 0.f;
                    }
                    o[p] = rv;
                }
                *reinterpret_cast<float4*>(&sout[c * OCSZ + (y0 + rr) * OS + x0]) =
                    make_float4(o[0], o[1], o[2], o[3]);
            }
        }
    }
}

__global__ __launch_bounds__(NTHREADS) void fused_conv_feat(
    const float* __restrict__ x,
    const float* __restrict__ w1, const float* __restrict__ b1,
    const float* __restrict__ w2, const float* __restrict__ b2,
    const float* __restrict__ w3, const float* __restrict__ b3,
    float* __restrict__ feat)
{
    const int tile = blockIdx.x;
    const int b    = blockIdx.y;
    const int tx   = tile & 3, ty = tile >> 2;
    const int tid  = threadIdx.x;

    __shared__ __align__(16) float lds[10032 + 9120];
    float* sIn = lds;
    float* sH1 = lds + 10032;
    float* sH2 = lds;
    float* sH3 = lds + 10032;

    const int gy0s = ty * 32 - 6, gx0s = tx * 64 - 6;
    for (int i = tid; i < 3 * 44 * 38; i += NTHREADS) {
        const int c   = i / 1672;
        const int rem = i - c * 1672;
        const int r   = rem / 38;
        const int k   = rem - r * 38;
        const int gy = gy0s + r, gx = gx0s + 2 * k;
        float2 v = make_float2(0.f, 0.f);
        if ((unsigned)gy < 256u) {
            const float* src = x + (((size_t)b * 3 + c) * 256 + gy) * 256;
            if (gx >= 0 && gx + 1 < 256) {
                v = *reinterpret_cast<const float2*>(src + gx);
            } else {
                if ((unsigned)gx < 256u)       v.x = src[gx];
                if ((unsigned)(gx + 1) < 256u) v.y = src[gx + 1];
            }
        }
        *reinterpret_cast<float2*>(&sIn[c * 3344 + r * 76 + 2 * k]) = v;
    }
    __syncthreads();

    conv5x5<3, 3, 72, 40, 76, 3344, 76, 3040, true>(sIn, sH1, w1, b1,
                                                    ty * 32 - 4, tx * 64 - 4, tid);
    __syncthreads();
    conv5x5<3, 3, 68, 36, 76, 3040, 76, 2736, true>(sH1, sH2, w2, b2,
                                                    ty * 32 - 2, tx * 64 - 2, tid);
    __syncthreads();
    conv5x5<3, 1, 64, 32, 76, 2736, 64, 2048, false>(sH2, sH3, w3, b3, 0, 0, tid);
    __syncthreads();

    const int wv   = tid >> 6;
    const int lane = tid & 63;
    const int py = wv >> 2, px = wv & 3;
    float s = 0.f;
#pragma unroll
    for (int k = 0; k < 4; ++k) {
        const int idx = lane + k * 64;
        const int r = idx >> 4, cc = idx & 15;
        s += sH3[(py * 16 + r) * 64 + px * 16 + cc];
    }
#pragma unroll
    for (int off = 32; off > 0; off >>= 1) s += __shfl_down(s, off, 64);
    if (lane == 0) {
        const int j = ty * 2 + py, i = tx * 4 + px;
        feat[(size_t)b * 256 + j * 16 + i] = s * (1.f / 256.f);
    }
}

// ---------------- MLP head ----------------
__global__ __launch_bounds__(64) void mlp_head(
    const float* __restrict__ feat,
    const float* __restrict__ wl1, const float* __restrict__ bl1,
    const float* __restrict__ wl2, const float* __restrict__ bl2,
    float* __restrict__ out)
{
    const int b = blockIdx.x;
    const int t = threadIdx.x;

    __shared__ float sF[256];
    __shared__ float sE[64];
    __shared__ float sL[8];
    __shared__ float sX[8];

    for (int i = t; i < 256; i += 64) sF[i] = feat[(size_t)b * 256 + i];
    __syncthreads();

    float acc = bl1[t];
    for (int k = 0; k < 256; ++k) acc = fmaf(sF[k], wl1[t * 256 + k], acc);
    sE[t] = acc;
    __syncthreads();

    if (t < 8) {
        float l = bl2[t];
#pragma unroll
        for (int k = 0; k < 64; ++k) l = fmaf(sE[k], wl2[t * 64 + k], l);
        sL[t] = l;
    }
    __syncthreads();

    if (t < 8) {
        float m = sL[0];
#pragma unroll
        for (int k = 1; k < 8; ++k) m = fmaxf(m, sL[k]);
        sX[t] = __expf(sL[t] - m);
    }
    __syncthreads();

    if (t < 8) {
        float sum = 0.f;
#pragma unroll
        for (int k = 0; k < 8; ++k) sum += sX[k];
        out[(size_t)b * 8 + t] = sX[t] / sum;
    }
}

extern "C" void kernel_launch(void* const* d_in, const int* in_sizes, int n_in,
                              void* d_out, int out_size, void* d_ws, size_t ws_size,
                              hipStream_t stream) {
    const float* x   = (const float*)d_in[0];
    const float* w1  = (const float*)d_in[1];
    const float* b1  = (const float*)d_in[2];
    const float* w2  = (const float*)d_in[3];
    const float* b2  = (const float*)d_in[4];
    const float* w3  = (const float*)d_in[5];
    const float* b3  = (const float*)d_in[6];
    const float* wl1 = (const float*)d_in[7];
    const float* bl1 = (const float*)d_in[8];
    const float* wl2 = (const float*)d_in[9];
    const float* bl2 = (const float*)d_in[10];
    float* out  = (float*)d_out;

    const size_t FEAT_B = 256u * 256u * 4u;                 // 262144
    const size_t H_B    = (size_t)256 * 3 * 256 * 256 * 2;  // 100663296
    float* feat = (float*)d_ws;

    if (ws_size >= FEAT_B + 2 * H_B) {
        unsigned short* h1 = (unsigned short*)((char*)d_ws + FEAT_B);
        unsigned short* h2 = (unsigned short*)((char*)d_ws + FEAT_B + H_B);
        dim3 g(4, 8, 256);
        conv_stage<false, 3, false><<<g, CT, 0, stream>>>(x,  w1, b1, h1, nullptr);
        conv_stage<true,  3, false><<<g, CT, 0, stream>>>(h1, w2, b2, h2, nullptr);
        conv_stage<true,  1, true ><<<g, CT, 0, stream>>>(h2, w3, b3, nullptr, feat);
    } else {
        dim3 g1(32, 256);
        fused_conv_feat<<<g1, NTHREADS, 0, stream>>>(x, w1, b1, w2, b2, w3, b3, feat);
    }
    mlp_head<<<256, 64, 0, stream>>>(feat, wl1, bl1, wl2, bl2, out);
}

// Round 5
// 380.632 us; speedup vs baseline: 2.5888x; 1.1819x over previous
//
#include <hip/hip_runtime.h>
#include <hip/hip_bf16.h>

// Round 5: split per-stage kernels (round-4 structure) with the round-3
// rolling-row inner loop (v[8] live, no v[6][8] scratch spill).
//   conv1: x(f32) -> h1(bf16); conv2: h1 -> h2(bf16); conv3+pool: h2 -> feat;
//   mlp: feat -> softmax. Fused round-3 fallback if ws_size too small.
// Conv kernels: 256 threads, 64x32 output tile, exactly 256 tasks of
// 2 rows x 4 cols x OC. 29.4 KB LDS -> 5 blocks/CU.

#define CT 256

static __device__ __forceinline__ unsigned short f2bf(float f) {
    __hip_bfloat16 h = __float2bfloat16(f);
    return *reinterpret_cast<unsigned short*>(&h);
}
static __device__ __forceinline__ float bf2f(unsigned short u) {
    __hip_bfloat16 h;
    *reinterpret_cast<unsigned short*>(&h) = u;
    return __bfloat162float(h);
}

// ---------------- split-path conv kernel ----------------
template<bool IN_BF16, int OC, bool POOL>
__global__ __launch_bounds__(CT) void conv_stage(
    const void* __restrict__ in_,
    const float* __restrict__ w, const float* __restrict__ bias,
    unsigned short* __restrict__ out_, float* __restrict__ feat)
{
    const int tx = blockIdx.x;     // 0..3   (x tiles of 64)
    const int ty = blockIdx.y;     // 0..7   (y tiles of 32)
    const int b  = blockIdx.z;     // image
    const int tid = threadIdx.x;

    __shared__ __align__(16) float sIn[3 * 36 * 68];   // 29376 B
    __shared__ float sPartial[16];

    const int gy0 = ty * 32, gx0 = tx * 64;

    // ---- stage 36 rows x 68 cols x 3 ch (zero-padded); predicates computed
    //      once per (r,k) position, reused for all 3 channels ----
    for (int pos = tid; pos < 36 * 34; pos += CT) {
        const int r  = pos / 34;
        const int k  = pos - r * 34;
        const int gy = gy0 - 2 + r;
        const int gx = gx0 - 2 + 2 * k;
        const bool yok = (unsigned)gy < 256u;
        const bool full = yok & (gx >= 0) & (gx + 1 < 256);
#pragma unroll
        for (int c = 0; c < 3; ++c) {
            float2 v = make_float2(0.f, 0.f);
            if (!IN_BF16) {
                const float* src = (const float*)in_ + (((size_t)b * 3 + c) * 256 + gy) * 256;
                if (full) {
                    v = *reinterpret_cast<const float2*>(src + gx);
                } else if (yok) {
                    if ((unsigned)gx < 256u)       v.x = src[gx];
                    if ((unsigned)(gx + 1) < 256u) v.y = src[gx + 1];
                }
            } else {
                const unsigned short* src =
                    (const unsigned short*)in_ + (((size_t)b * 3 + c) * 256 + gy) * 256;
                if (full) {
                    const unsigned int u = *reinterpret_cast<const unsigned int*>(src + gx);
                    v.x = bf2f((unsigned short)(u & 0xffffu));
                    v.y = bf2f((unsigned short)(u >> 16));
                } else if (yok) {
                    if ((unsigned)gx < 256u)       v.x = bf2f(src[gx]);
                    if ((unsigned)(gx + 1) < 256u) v.y = bf2f(src[gx + 1]);
                }
            }
            *reinterpret_cast<float2*>(&sIn[(c * 36 + r) * 68 + 2 * k]) = v;
        }
    }
    __syncthreads();

    // ---- compute: task (ry,qx), 2 rows x 4 cols x OC; rolling row window ----
    const int ry = tid >> 4, qx = tid & 15;
    const int y0 = ry * 2,  x0 = qx * 4;

    float acc0[OC][4], acc1[OC][4];
#pragma unroll
    for (int c = 0; c < OC; ++c) {
        const float bb = bias[c];
#pragma unroll
        for (int p = 0; p < 4; ++p) { acc0[c][p] = bb; acc1[c][p] = bb; }
    }

#pragma unroll
    for (int ic = 0; ic < 3; ++ic) {
        const float* base = &sIn[ic * 2448 + y0 * 68 + x0];
#pragma unroll
        for (int rw = 0; rw < 6; ++rw) {
            const float4 a4 = *reinterpret_cast<const float4*>(base + rw * 68);
            const float4 b4 = *reinterpret_cast<const float4*>(base + rw * 68 + 4);
            const float v[8] = {a4.x, a4.y, a4.z, a4.w, b4.x, b4.y, b4.z, b4.w};
#pragma unroll
            for (int kx = 0; kx < 5; ++kx) {
#pragma unroll
                for (int c = 0; c < OC; ++c) {
                    if (rw < 5) {               // ky = rw feeds output row 0
                        const float wv = w[((c * 3 + ic) * 5 + rw) * 5 + kx];
#pragma unroll
                        for (int p = 0; p < 4; ++p)
                            acc0[c][p] = fmaf(v[p + kx], wv, acc0[c][p]);
                    }
                    if (rw >= 1) {              // ky = rw-1 feeds output row 1
                        const float wv = w[((c * 3 + ic) * 5 + (rw - 1)) * 5 + kx];
#pragma unroll
                        for (int p = 0; p < 4; ++p)
                            acc1[c][p] = fmaf(v[p + kx], wv, acc1[c][p]);
                    }
                }
            }
        }
    }

    if (!POOL) {
#pragma unroll
        for (int rr = 0; rr < 2; ++rr) {
            const int gy = gy0 + y0 + rr;
#pragma unroll
            for (int c = 0; c < OC; ++c) {
                const float* a = (rr == 0) ? acc0[c] : acc1[c];
                const unsigned int lo =
                    (unsigned int)f2bf(fmaxf(a[0], 0.f)) |
                    ((unsigned int)f2bf(fmaxf(a[1], 0.f)) << 16);
                const unsigned int hi =
                    (unsigned int)f2bf(fmaxf(a[2], 0.f)) |
                    ((unsigned int)f2bf(fmaxf(a[3], 0.f)) << 16);
                unsigned short* dst =
                    out_ + (((size_t)b * OC + c) * 256 + gy) * 256 + gx0 + x0;
                *reinterpret_cast<uint2*>(dst) = make_uint2(lo, hi);
            }
        }
    } else {
        float s = 0.f;
#pragma unroll
        for (int p = 0; p < 4; ++p) s += fmaxf(acc0[0][p], 0.f) + fmaxf(acc1[0][p], 0.f);
        // butterfly over the 16 lanes sharing a patch (qx bits 0-1, ry bits 0-1)
        s += __shfl_xor(s, 1, 64);
        s += __shfl_xor(s, 2, 64);
        s += __shfl_xor(s, 16, 64);
        s += __shfl_xor(s, 32, 64);
        const int wv = tid >> 6, l = tid & 63;
        if ((l & 3) == 0 && l < 16) sPartial[wv * 4 + (l >> 2)] = s;
        __syncthreads();
        if (tid < 8) {
            const int py = tid >> 2, px = tid & 3;
            const float v2 = sPartial[(2 * py) * 4 + px] + sPartial[(2 * py + 1) * 4 + px];
            const int j = ty * 2 + py, i = tx * 4 + px;
            feat[(size_t)b * 256 + j * 16 + i] = v2 * (1.f / 256.f);
        }
    }
}

// ---------------- fused fallback (round-3 kernel) ----------------
#define NTHREADS 512

template<int ICn, int OCn, int OW, int OH, int IS, int ICSZ, int OS, int OCSZ, bool MASK>
__device__ __forceinline__ void conv5x5(
    const float* __restrict__ sin, float* __restrict__ sout,
    const float* __restrict__ w, const float* __restrict__ bias,
    int gy0, int gx0, int tid)
{
    constexpr int QX = OW / 4;
    constexpr int RY = OH / 2;
    constexpr int TASKS = QX * RY;
    if (tid < TASKS) {
        const int ry = tid / QX;
        const int qx = tid - ry * QX;
        const int y0 = ry * 2, x0 = qx * 4;
        float acc[2][OCn][4];
#pragma unroll
        for (int c = 0; c < OCn; ++c) {
            const float bb = bias[c];
#pragma unroll
            for (int p = 0; p < 4; ++p) { acc[0][c][p] = bb; acc[1][c][p] = bb; }
        }
#pragma unroll
        for (int ic = 0; ic < ICn; ++ic) {
            const float* base = sin + ic * ICSZ + y0 * IS + x0;
#pragma unroll
            for (int r = 0; r < 6; ++r) {
                const float4 a4 = *reinterpret_cast<const float4*>(base + r * IS);
                const float4 b4 = *reinterpret_cast<const float4*>(base + r * IS + 4);
                const float v[8] = {a4.x, a4.y, a4.z, a4.w, b4.x, b4.y, b4.z, b4.w};
#pragma unroll
                for (int kx = 0; kx < 5; ++kx)
#pragma unroll
                    for (int c = 0; c < OCn; ++c) {
                        if (r < 5) {
                            const float wv = w[((c * ICn + ic) * 5 + r) * 5 + kx];
#pragma unroll
                            for (int p = 0; p < 4; ++p)
                                acc[0][c][p] = fmaf(v[p + kx], wv, acc[0][c][p]);
                        }
                        if (r >= 1) {
                            const float wv = w[((c * ICn + ic) * 5 + (r - 1)) * 5 + kx];
#pragma unroll
                            for (int p = 0; p < 4; ++p)
                                acc[1][c][p] = fmaf(v[p + kx], wv, acc[1][c][p]);
                        }
                    }
            }
        }
#pragma unroll
        for (int rr = 0; rr < 2; ++rr) {
            const int gy = gy0 + y0 + rr;
#pragma unroll
            for (int c = 0; c < OCn; ++c) {
                float o[4];
#pragma unroll
                for (int p = 0; p < 4; ++p) {
                    float rv = fmaxf(acc[rr][c][p], 0.f);
                    if (MASK) {
                        const int gx = gx0 + x0 + p;
                        const bool ok = ((unsigned)gy < 256u) & ((unsigned)gx < 256u);
                        rv = ok ? rv : 0.f;
                    }
                    o[p] = rv;
                }
                *reinterpret_cast<float4*>(&sout[c * OCSZ + (y0 + rr) * OS + x0]) =
                    make_float4(o[0], o[1], o[2], o[3]);
            }
        }
    }
}

__global__ __launch_bounds__(NTHREADS) void fused_conv_feat(
    const float* __restrict__ x,
    const float* __restrict__ w1, const float* __restrict__ b1,
    const float* __restrict__ w2, const float* __restrict__ b2,
    const float* __restrict__ w3, const float* __restrict__ b3,
    float* __restrict__ feat)
{
    const int tile = blockIdx.x;
    const int b    = blockIdx.y;
    const int tx   = tile & 3, ty = tile >> 2;
    const int tid  = threadIdx.x;

    __shared__ __align__(16) float lds[10032 + 9120];
    float* sIn = lds;
    float* sH1 = lds + 10032;
    float* sH2 = lds;
    float* sH3 = lds + 10032;

    const int gy0s = ty * 32 - 6, gx0s = tx * 64 - 6;
    for (int i = tid; i < 3 * 44 * 38; i += NTHREADS) {
        const int c   = i / 1672;
        const int rem = i - c * 1672;
        const int r   = rem / 38;
        const int k   = rem - r * 38;
        const int gy = gy0s + r, gx = gx0s + 2 * k;
        float2 v = make_float2(0.f, 0.f);
        if ((unsigned)gy < 256u) {
            const float* src = x + (((size_t)b * 3 + c) * 256 + gy) * 256;
            if (gx >= 0 && gx + 1 < 256) {
                v = *reinterpret_cast<const float2*>(src + gx);
            } else {
                if ((unsigned)gx < 256u)       v.x = src[gx];
                if ((unsigned)(gx + 1) < 256u) v.y = src[gx + 1];
            }
        }
        *reinterpret_cast<float2*>(&sIn[c * 3344 + r * 76 + 2 * k]) = v;
    }
    __syncthreads();

    conv5x5<3, 3, 72, 40, 76, 3344, 76, 3040, true>(sIn, sH1, w1, b1,
                                                    ty * 32 - 4, tx * 64 - 4, tid);
    __syncthreads();
    conv5x5<3, 3, 68, 36, 76, 3040, 76, 2736, true>(sH1, sH2, w2, b2,
                                                    ty * 32 - 2, tx * 64 - 2, tid);
    __syncthreads();
    conv5x5<3, 1, 64, 32, 76, 2736, 64, 2048, false>(sH2, sH3, w3, b3, 0, 0, tid);
    __syncthreads();

    const int wv   = tid >> 6;
    const int lane = tid & 63;
    const int py = wv >> 2, px = wv & 3;
    float s = 0.f;
#pragma unroll
    for (int k = 0; k < 4; ++k) {
        const int idx = lane + k * 64;
        const int r = idx >> 4, cc = idx & 15;
        s += sH3[(py * 16 + r) * 64 + px * 16 + cc];
    }
#pragma unroll
    for (int off = 32; off > 0; off >>= 1) s += __shfl_down(s, off, 64);
    if (lane == 0) {
        const int j = ty * 2 + py, i = tx * 4 + px;
        feat[(size_t)b * 256 + j * 16 + i] = s * (1.f / 256.f);
    }
}

// ---------------- MLP head ----------------
__global__ __launch_bounds__(64) void mlp_head(
    const float* __restrict__ feat,
    const float* __restrict__ wl1, const float* __restrict__ bl1,
    const float* __restrict__ wl2, const float* __restrict__ bl2,
    float* __restrict__ out)
{
    const int b = blockIdx.x;
    const int t = threadIdx.x;

    __shared__ float sF[256];
    __shared__ float sE[64];
    __shared__ float sL[8];
    __shared__ float sX[8];

    for (int i = t; i < 256; i += 64) sF[i] = feat[(size_t)b * 256 + i];
    __syncthreads();

    float acc = bl1[t];
    for (int k = 0; k < 256; ++k) acc = fmaf(sF[k], wl1[t * 256 + k], acc);
    sE[t] = acc;
    __syncthreads();

    if (t < 8) {
        float l = bl2[t];
#pragma unroll
        for (int k = 0; k < 64; ++k) l = fmaf(sE[k], wl2[t * 64 + k], l);
        sL[t] = l;
    }
    __syncthreads();

    if (t < 8) {
        float m = sL[0];
#pragma unroll
        for (int k = 1; k < 8; ++k) m = fmaxf(m, sL[k]);
        sX[t] = __expf(sL[t] - m);
    }
    __syncthreads();

    if (t < 8) {
        float sum = 0.f;
#pragma unroll
        for (int k = 0; k < 8; ++k) sum += sX[k];
        out[(size_t)b * 8 + t] = sX[t] / sum;
    }
}

extern "C" void kernel_launch(void* const* d_in, const int* in_sizes, int n_in,
                              void* d_out, int out_size, void* d_ws, size_t ws_size,
                              hipStream_t stream) {
    const float* x   = (const float*)d_in[0];
    const float* w1  = (const float*)d_in[1];
    const float* b1  = (const float*)d_in[2];
    const float* w2  = (const float*)d_in[3];
    const float* b2  = (const float*)d_in[4];
    const float* w3  = (const float*)d_in[5];
    const float* b3  = (const float*)d_in[6];
    const float* wl1 = (const float*)d_in[7];
    const float* bl1 = (const float*)d_in[8];
    const float* wl2 = (const float*)d_in[9];
    const float* bl2 = (const float*)d_in[10];
    float* out  = (float*)d_out;

    const size_t FEAT_B = 256u * 256u * 4u;                 // 262144
    const size_t H_B    = (size_t)256 * 3 * 256 * 256 * 2;  // 100663296
    float* feat = (float*)d_ws;

    if (ws_size >= FEAT_B + 2 * H_B) {
        unsigned short* h1 = (unsigned short*)((char*)d_ws + FEAT_B);
        unsigned short* h2 = (unsigned short*)((char*)d_ws + FEAT_B + H_B);
        dim3 g(4, 8, 256);
        conv_stage<false, 3, false><<<g, CT, 0, stream>>>(x,  w1, b1, h1, nullptr);
        conv_stage<true,  3, false><<<g, CT, 0, stream>>>(h1, w2, b2, h2, nullptr);
        conv_stage<true,  1, true ><<<g, CT, 0, stream>>>(h2, w3, b3, nullptr, feat);
    } else {
        dim3 g1(32, 256);
        fused_conv_feat<<<g1, NTHREADS, 0, stream>>>(x, w1, b1, w2, b2, w3, b3, feat);
    }
    mlp_head<<<256, 64, 0, stream>>>(feat, wl1, bl1, wl2, bl2, out);
}